// Round 7
// baseline (626.708 us; speedup 1.0000x reference)
//
#include <hip/hip_runtime.h>
#include <hip/hip_fp16.h>
#include <math.h>

#define NN 500000
#define BSZ 512                      // nodes per bucket
#define NBK ((NN + BSZ - 1) / BSZ)   // 977 buckets
#define SCH 8192                     // staging chunk (edges) = part granularity
#define KMAX 20                      // max recs/thread in sort (20*1024 >> max bucket ~16.9K)
#define SZMAX 17408                  // LDS sort buffer (max bucket ~16.2K edges + pad)

typedef __attribute__((ext_vector_type(4))) _Float16 half4;
typedef __attribute__((ext_vector_type(2))) _Float16 half2v;
typedef __attribute__((ext_vector_type(4))) int int4v;
typedef __attribute__((ext_vector_type(2))) float float2v;

// ---------- pass 1: per-chunk bucket histogram; NO global atomics ----------
__global__ void hist_kernel(const int* __restrict__ col, unsigned short* __restrict__ blkCnt,
                            int E, int nch) {
    __shared__ int cnt[4 * 1024];
    int t = threadIdx.x;
    for (int i = t; i < 4096; i += 256) cnt[i] = 0;
    __syncthreads();
    int base = blockIdx.x * (4 * SCH);
    int end = base + 4 * SCH; if (end > E) end = E;
    for (int j = base + t * 4; j < end; j += 1024) {
        int4v c = __builtin_nontemporal_load(reinterpret_cast<const int4v*>(col + j));
        int sub = (j - base) >> 13;                        // chunk within block (0..3)
        atomicAdd(&cnt[sub * 1024 + (c.x >> 9)], 1);
        atomicAdd(&cnt[sub * 1024 + (c.y >> 9)], 1);
        atomicAdd(&cnt[sub * 1024 + (c.z >> 9)], 1);
        atomicAdd(&cnt[sub * 1024 + (c.w >> 9)], 1);
    }
    __syncthreads();
    int chunk0 = blockIdx.x * 4;
#pragma unroll
    for (int s = 0; s < 4; ++s) {
        int c = chunk0 + s;
        if (c >= nch) break;
        for (int b = t; b < 1024; b += 256)
            blkCnt[(size_t)c * 1024 + b] = (unsigned short)cnt[s * 1024 + b];
    }
}

// ---------- pass 2: per-bucket SEQUENTIAL prefix across chunks, in place ---
__global__ void colscan_kernel(unsigned short* __restrict__ blkCnt,
                               int* __restrict__ bucketTotal, int nch) {
    __shared__ int ls[64][5];
    int t = threadIdx.x;
    int cl = t & 3;            // bucket lane (4 buckets/block)
    int bk = t >> 2;           // strip 0..63
    int b = blockIdx.x * 4 + cl;
    int cps = (nch + 63) >> 6; // chunks per strip (contiguous)
    int c0 = bk * cps;
    int c1 = c0 + cps; if (c1 > nch) c1 = nch;
    int run = 0;
    for (int c = c0; c < c1; ++c)
        run += blkCnt[(size_t)c * 1024 + b];
    ls[bk][cl] = run;
    __syncthreads();
    if (t < 4) {               // serial exclusive scan over the 64 strips
        int r = 0;
        for (int k = 0; k < 64; ++k) { int v = ls[k][t]; ls[k][t] = r; r += v; }
        bucketTotal[blockIdx.x * 4 + t] = r;
    }
    __syncthreads();
    int running = ls[bk][cl];
    for (int c = c0; c < c1; ++c) {
        size_t idx = (size_t)c * 1024 + b;
        int v = blkCnt[idx];
        blkCnt[idx] = (unsigned short)running;   // prefix <= bucket total ~17K < 65536
        running += v;
    }
}

// ---------- pass 3: exclusive scan of 1024 bucket totals (1 block) ---------
__global__ void scan_kernel(const int* __restrict__ bucketTotal, int* __restrict__ bucketStart) {
    __shared__ int ls[1024];
    int t = threadIdx.x;
    int v = bucketTotal[t];
    ls[t] = v;
    __syncthreads();
    for (int off = 1; off < 1024; off <<= 1) {
        int u = (t >= off) ? ls[t - off] : 0;
        __syncthreads();
        ls[t] += u;
        __syncthreads();
    }
    bucketStart[t] = ls[t] - v;  // exclusive
}

// ---------- pass 4: partition with LDS staging; NO global atomics ----------
__global__ __launch_bounds__(256) void part_kernel(const int* __restrict__ row,
                                                   const int* __restrict__ col,
                                                   const int* __restrict__ bucketStart,
                                                   const int* __restrict__ bucketTotal,
                                                   const unsigned short* __restrict__ blkPre,
                                                   int* __restrict__ recs, int E, int nch) {
    __shared__ int gbase[1024];
    __shared__ int lexcl[1024];
    __shared__ int cursor[1024];
    __shared__ int ts[256];
    __shared__ int srt[SCH];
    __shared__ unsigned short bkt[SCH];
    int t = threadIdx.x;
    int chunk = blockIdx.x;
    const unsigned short* pre = blkPre + (size_t)chunk * 1024;
    const unsigned short* nxt = blkPre + (size_t)(chunk + 1) * 1024;  // pad row exists
    bool last = (chunk == nch - 1);
    int myc[4];
#pragma unroll
    for (int k = 0; k < 4; ++k) {
        int b = t * 4 + k;
        int p = pre[b];
        int n = last ? bucketTotal[b] : (int)nxt[b];
        myc[k] = n - p;
        gbase[b] = bucketStart[b] + p;
    }
    int tsum = myc[0] + myc[1] + myc[2] + myc[3];
    ts[t] = tsum;
    __syncthreads();
    for (int off = 1; off < 256; off <<= 1) {
        int u = (t >= off) ? ts[t - off] : 0;
        __syncthreads();
        ts[t] += u;
        __syncthreads();
    }
    int r = ts[t] - tsum;      // exclusive over threads
#pragma unroll
    for (int k = 0; k < 4; ++k) {
        int b = t * 4 + k;
        lexcl[b] = r;
        cursor[b] = r;
        r += myc[k];
    }
    __syncthreads();
    // phase 1: rank + stage into LDS (bucket-sorted)
    int base = chunk * SCH;
    int end = base + SCH; if (end > E) end = E;
    for (int j = base + t * 4; j < end; j += 1024) {
        int4v rr = __builtin_nontemporal_load(reinterpret_cast<const int4v*>(row + j));
        int4v cc = __builtin_nontemporal_load(reinterpret_cast<const int4v*>(col + j));
        int b, rk;
        b = cc.x >> 9; rk = atomicAdd(&cursor[b], 1); srt[rk] = (rr.x << 9) | (cc.x & 511); bkt[rk] = (unsigned short)b;
        b = cc.y >> 9; rk = atomicAdd(&cursor[b], 1); srt[rk] = (rr.y << 9) | (cc.y & 511); bkt[rk] = (unsigned short)b;
        b = cc.z >> 9; rk = atomicAdd(&cursor[b], 1); srt[rk] = (rr.z << 9) | (cc.z & 511); bkt[rk] = (unsigned short)b;
        b = cc.w >> 9; rk = atomicAdd(&cursor[b], 1); srt[rk] = (rr.w << 9) | (cc.w & 511); bkt[rk] = (unsigned short)b;
    }
    __syncthreads();
    // phase 2: flush contiguous bucket runs
    int m = end - base;
    for (int p = t; p < m; p += 256) {
        int b = bkt[p];
        recs[gbase[b] + (p - lexcl[b])] = srt[p];
    }
}

// ---------- pass 5: per-bucket counting sort + degree-rank permutation -----
// LDS-staged output (round 6). NEW: within-bucket counting-rank of nodes by
// degree -> nodePerm, so agg waves get degree-matched lanes (kills the
// ~1.4x lane-imbalance inflation in the gather loops).
__global__ __launch_bounds__(1024) void sort_kernel(const int* __restrict__ bucketStart,
                                                    const int* __restrict__ bucketTotal,
                                                    int* __restrict__ recs,
                                                    float* __restrict__ dinv,
                                                    int* __restrict__ nodeStart,
                                                    int* __restrict__ nodePerm, int N, int E) {
    __shared__ int cnt[BSZ];
    __shared__ int sc[BSZ];
    __shared__ int dh[129];
    __shared__ int srtS[SZMAX];
    int t = threadIdx.x, b = blockIdx.x;
    int s = bucketStart[b], m = bucketTotal[b];
    int v[KMAX];
#pragma unroll
    for (int k = 0; k < KMAX; ++k) {
        int idx = t + k * 1024;
        v[k] = (idx < m) ? recs[s + idx] : -1;
    }
    if (t < BSZ) cnt[t] = 0;
    __syncthreads();
#pragma unroll
    for (int k = 0; k < KMAX; ++k)
        if (v[k] >= 0) atomicAdd(&cnt[v[k] & 511], 1);
    __syncthreads();
    if (t < BSZ) sc[t] = cnt[t];
    __syncthreads();
    for (int off = 1; off < BSZ; off <<= 1) {
        int u = 0;
        if (t < BSZ && t >= off) u = sc[t - off];
        __syncthreads();
        if (t < BSZ) sc[t] += u;
        __syncthreads();
    }
    int node = b * BSZ + t;
    bool valid = (t < BSZ) && (node < N);
    int myDeg = 0;
    if (t < BSZ) {
        myDeg = cnt[t];
        int excl = sc[t] - myDeg;
        if (node < N) {
            nodeStart[node] = s + excl;
            dinv[node] = rsqrtf((float)myDeg + 1.0f);
        }
        cnt[t] = excl;
    }
    if (b == NBK - 1 && t == 0) nodeStart[N] = E;
    // degree-rank permutation (129-bin counting sort over degrees)
    if (t < 129) dh[t] = 0;
    __syncthreads();
    int dmin = myDeg > 128 ? 128 : myDeg;
    if (valid) atomicAdd(&dh[dmin], 1);
    __syncthreads();
    if (t == 0) {
        int r = 0;
        for (int k = 0; k < 129; ++k) { int u = dh[k]; dh[k] = r; r += u; }
    }
    __syncthreads();
    if (valid) {
        int rk = atomicAdd(&dh[dmin], 1);
        nodePerm[b * BSZ + rk] = node;   // dense: bucket slots == #valid nodes
    }
    __syncthreads();
#pragma unroll
    for (int k = 0; k < KMAX; ++k) {
        if (v[k] >= 0) {
            int rk = atomicAdd(&cnt[v[k] & 511], 1);
            srtS[rk] = v[k] >> 9;          // random LDS write: ~free
        }
    }
    __syncthreads();
    for (int p = t; p < m; p += 1024)      // coalesced global write
        recs[s + p] = srtS[p];
}

// ---------- prep: g1 = fp16( dinv * (x @ W1) ) -----------------------------
__global__ __launch_bounds__(256) void prep_kernel(const float* __restrict__ x,
                                                   const float* __restrict__ W1,
                                                   const float* __restrict__ dinv,
                                                   half4* __restrict__ g1h, int N) {
    __shared__ float xs[256 * 9];
    int t = threadIdx.x;
    int base = blockIdx.x * 256;
    int nval = (N - base < 256 ? N - base : 256) * 9;
    const float* xb = x + (size_t)base * 9;
    for (int k = t; k < nval; k += 256) xs[k] = xb[k];
    __syncthreads();
    int i = base + t;
    if (i >= N) return;
    float d = dinv[i];
    float acc0 = 0.f, acc1 = 0.f, acc2 = 0.f, acc3 = 0.f;
#pragma unroll
    for (int k = 0; k < 9; ++k) {
        float xv = xs[t * 9 + k];
        acc0 += xv * W1[k * 4 + 0];
        acc1 += xv * W1[k * 4 + 1];
        acc2 += xv * W1[k * 4 + 2];
        acc3 += xv * W1[k * 4 + 3];
    }
    half4 h;
    h.x = (_Float16)(d * acc0);
    h.y = (_Float16)(d * acc1);
    h.z = (_Float16)(d * acc2);
    h.w = (_Float16)(d * acc3);
    g1h[i] = h;
}

// ---------- agg layer 1: CSR gather, degree-matched lanes ------------------
#define NTL(p) __builtin_nontemporal_load(p)

__global__ __launch_bounds__(256) void agg1_kernel(const int* __restrict__ nodeStart,
                                                   const int* __restrict__ srows,
                                                   const float* __restrict__ dinv,
                                                   const half4* __restrict__ g1h,
                                                   const float* __restrict__ b1,
                                                   const float* __restrict__ W2,
                                                   const int* __restrict__ nodePerm,
                                                   half2v* __restrict__ g2h, int N) {
    int gid = blockIdx.x * blockDim.x + threadIdx.x;
    if (gid >= N) return;
    int i = nodePerm[gid];     // wave lanes get degree-adjacent nodes
    int s = nodeStart[i], e = nodeStart[i + 1];
    float a0 = 0.f, a1 = 0.f, a2 = 0.f, a3 = 0.f;
    int j = s;
    // scalar prologue up to 16B alignment
    for (; j < e && (j & 3); ++j) {
        half4 g = g1h[NTL(srows + j)];
        a0 += (float)g.x; a1 += (float)g.y; a2 += (float)g.z; a3 += (float)g.w;
    }
    // 16-edge chunks: 16 independent gathers per batch
    for (; j + 15 < e; j += 16) {
        int4v q0 = NTL(reinterpret_cast<const int4v*>(srows + j));
        int4v q1 = NTL(reinterpret_cast<const int4v*>(srows + j + 4));
        int4v q2 = NTL(reinterpret_cast<const int4v*>(srows + j + 8));
        int4v q3 = NTL(reinterpret_cast<const int4v*>(srows + j + 12));
        half4 g0 = g1h[q0.x], g1 = g1h[q0.y], g2 = g1h[q0.z], g3 = g1h[q0.w];
        half4 g4 = g1h[q1.x], g5 = g1h[q1.y], g6 = g1h[q1.z], g7 = g1h[q1.w];
        half4 g8 = g1h[q2.x], g9 = g1h[q2.y], gA = g1h[q2.z], gB = g1h[q2.w];
        half4 gC = g1h[q3.x], gD = g1h[q3.y], gE = g1h[q3.z], gF = g1h[q3.w];
        a0 += (((float)g0.x + (float)g1.x) + ((float)g2.x + (float)g3.x)) +
              (((float)g4.x + (float)g5.x) + ((float)g6.x + (float)g7.x)) +
              (((float)g8.x + (float)g9.x) + ((float)gA.x + (float)gB.x)) +
              (((float)gC.x + (float)gD.x) + ((float)gE.x + (float)gF.x));
        a1 += (((float)g0.y + (float)g1.y) + ((float)g2.y + (float)g3.y)) +
              (((float)g4.y + (float)g5.y) + ((float)g6.y + (float)g7.y)) +
              (((float)g8.y + (float)g9.y) + ((float)gA.y + (float)gB.y)) +
              (((float)gC.y + (float)gD.y) + ((float)gE.y + (float)gF.y));
        a2 += (((float)g0.z + (float)g1.z) + ((float)g2.z + (float)g3.z)) +
              (((float)g4.z + (float)g5.z) + ((float)g6.z + (float)g7.z)) +
              (((float)g8.z + (float)g9.z) + ((float)gA.z + (float)gB.z)) +
              (((float)gC.z + (float)gD.z) + ((float)gE.z + (float)gF.z));
        a3 += (((float)g0.w + (float)g1.w) + ((float)g2.w + (float)g3.w)) +
              (((float)g4.w + (float)g5.w) + ((float)g6.w + (float)g7.w)) +
              (((float)g8.w + (float)g9.w) + ((float)gA.w + (float)gB.w)) +
              (((float)gC.w + (float)gD.w) + ((float)gE.w + (float)gF.w));
    }
    for (; j + 3 < e; j += 4) {
        int4v r4 = NTL(reinterpret_cast<const int4v*>(srows + j));
        half4 g0 = g1h[r4.x];
        half4 g1 = g1h[r4.y];
        half4 g2 = g1h[r4.z];
        half4 g3 = g1h[r4.w];
        a0 += ((float)g0.x + (float)g1.x) + ((float)g2.x + (float)g3.x);
        a1 += ((float)g0.y + (float)g1.y) + ((float)g2.y + (float)g3.y);
        a2 += ((float)g0.z + (float)g1.z) + ((float)g2.z + (float)g3.z);
        a3 += ((float)g0.w + (float)g1.w) + ((float)g2.w + (float)g3.w);
    }
    for (; j < e; ++j) {
        half4 g = g1h[NTL(srows + j)];
        a0 += (float)g.x; a1 += (float)g.y; a2 += (float)g.z; a3 += (float)g.w;
    }
    half4 self = g1h[i];
    float di = dinv[i];
    float t0 = tanhf(di * (a0 + (float)self.x) + b1[0]);
    float t1 = tanhf(di * (a1 + (float)self.y) + b1[1]);
    float t2 = tanhf(di * (a2 + (float)self.z) + b1[2]);
    float t3 = tanhf(di * (a3 + (float)self.w) + b1[3]);
    float o0 = t0 * W2[0] + t1 * W2[2] + t2 * W2[4] + t3 * W2[6];
    float o1 = t0 * W2[1] + t1 * W2[3] + t2 * W2[5] + t3 * W2[7];
    half2v g2o;
    g2o.x = (_Float16)(di * o0);
    g2o.y = (_Float16)(di * o1);
    g2h[i] = g2o;
}

// ---------- agg layer 2: CSR gather, degree-matched lanes ------------------
__global__ __launch_bounds__(256) void agg2_kernel(const int* __restrict__ nodeStart,
                                                   const int* __restrict__ srows,
                                                   const float* __restrict__ dinv,
                                                   const half2v* __restrict__ g2h,
                                                   const float* __restrict__ b2,
                                                   const int* __restrict__ nodePerm,
                                                   float* __restrict__ out, int N) {
    int gid = blockIdx.x * blockDim.x + threadIdx.x;
    if (gid >= N) return;
    int i = nodePerm[gid];
    int s = nodeStart[i], e = nodeStart[i + 1];
    float a0 = 0.f, a1 = 0.f;
    int j = s;
    for (; j < e && (j & 3); ++j) {
        half2v g = g2h[NTL(srows + j)];
        a0 += (float)g.x; a1 += (float)g.y;
    }
    for (; j + 15 < e; j += 16) {
        int4v q0 = NTL(reinterpret_cast<const int4v*>(srows + j));
        int4v q1 = NTL(reinterpret_cast<const int4v*>(srows + j + 4));
        int4v q2 = NTL(reinterpret_cast<const int4v*>(srows + j + 8));
        int4v q3 = NTL(reinterpret_cast<const int4v*>(srows + j + 12));
        half2v g0 = g2h[q0.x], g1 = g2h[q0.y], g2 = g2h[q0.z], g3 = g2h[q0.w];
        half2v g4 = g2h[q1.x], g5 = g2h[q1.y], g6 = g2h[q1.z], g7 = g2h[q1.w];
        half2v g8 = g2h[q2.x], g9 = g2h[q2.y], gA = g2h[q2.z], gB = g2h[q2.w];
        half2v gC = g2h[q3.x], gD = g2h[q3.y], gE = g2h[q3.z], gF = g2h[q3.w];
        a0 += (((float)g0.x + (float)g1.x) + ((float)g2.x + (float)g3.x)) +
              (((float)g4.x + (float)g5.x) + ((float)g6.x + (float)g7.x)) +
              (((float)g8.x + (float)g9.x) + ((float)gA.x + (float)gB.x)) +
              (((float)gC.x + (float)gD.x) + ((float)gE.x + (float)gF.x));
        a1 += (((float)g0.y + (float)g1.y) + ((float)g2.y + (float)g3.y)) +
              (((float)g4.y + (float)g5.y) + ((float)g6.y + (float)g7.y)) +
              (((float)g8.y + (float)g9.y) + ((float)gA.y + (float)gB.y)) +
              (((float)gC.y + (float)gD.y) + ((float)gE.y + (float)gF.y));
    }
    for (; j + 3 < e; j += 4) {
        int4v r4 = NTL(reinterpret_cast<const int4v*>(srows + j));
        half2v g0 = g2h[r4.x];
        half2v g1 = g2h[r4.y];
        half2v g2 = g2h[r4.z];
        half2v g3 = g2h[r4.w];
        a0 += ((float)g0.x + (float)g1.x) + ((float)g2.x + (float)g3.x);
        a1 += ((float)g0.y + (float)g1.y) + ((float)g2.y + (float)g3.y);
    }
    for (; j < e; ++j) {
        half2v g = g2h[NTL(srows + j)];
        a0 += (float)g.x; a1 += (float)g.y;
    }
    half2v self = g2h[i];
    float di = dinv[i];
    float2v o;
    o.x = di * (a0 + (float)self.x) + b2[0];
    o.y = di * (a1 + (float)self.y) + b2[1];
    __builtin_nontemporal_store(o, reinterpret_cast<float2v*>(out) + i);
}

extern "C" void kernel_launch(void* const* d_in, const int* in_sizes, int n_in,
                              void* d_out, int out_size, void* d_ws, size_t ws_size,
                              hipStream_t stream) {
    const float* x  = (const float*)d_in[0];
    const int*   ei = (const int*)d_in[1];   // [2, E] int32
    const float* W1 = (const float*)d_in[2];
    const float* b1 = (const float*)d_in[3];
    const float* W2 = (const float*)d_in[4];
    const float* b2 = (const float*)d_in[5];
    float* out = (float*)d_out;

    const int N = NN;
    const int E = in_sizes[1] / 2;           // 16,000,000
    const int* row = ei;
    const int* col = ei + E;

    const int nch = (E + SCH - 1) / SCH;     // 1954 staging chunks

    char* ws = (char*)d_ws;
    size_t off = 0;
    int* bucketTotal = (int*)(ws + off);            off += 4096;
    int* bucketStart = (int*)(ws + off);            off += 4096;
    off = 16384;
    unsigned short* blkCnt = (unsigned short*)(ws + off);
    off += (size_t)(nch + 1) * 1024 * 2;            // ~4.0 MB (pad row for part's nxt)
    off = (off + 15) & ~(size_t)15;
    float*  dinv      = (float*)(ws + off);         off += (size_t)NN * 4;
    off = (off + 15) & ~(size_t)15;
    half4*  g1h       = (half4*)(ws + off);         off += (size_t)NN * 8;
    off = (off + 15) & ~(size_t)15;
    half2v* g2h       = (half2v*)(ws + off);        off += (size_t)NN * 4;
    off = (off + 15) & ~(size_t)15;
    int*    nodeStart = (int*)(ws + off);           off += (size_t)(NN + 1) * 4;
    off = (off + 15) & ~(size_t)15;
    int*    nodePerm  = (int*)(ws + off);           off += (size_t)NN * 4;
    off = (off + 15) & ~(size_t)15;
    int*    recs      = (int*)(ws + off);

    // zero the blkCnt pad row (speculatively read by part's nxt on the last chunk)
    (void)hipMemsetAsync(blkCnt + (size_t)nch * 1024, 0, 2048, stream);

    const int ngrid = (N + 255) / 256;
    const int hgrid = (nch + 3) / 4;

    hist_kernel   <<<hgrid, 256, 0, stream>>>(col, blkCnt, E, nch);
    colscan_kernel<<<256, 256, 0, stream>>>(blkCnt, bucketTotal, nch);
    scan_kernel   <<<1, 1024, 0, stream>>>(bucketTotal, bucketStart);
    part_kernel   <<<nch, 256, 0, stream>>>(row, col, bucketStart, bucketTotal, blkCnt, recs, E, nch);
    sort_kernel   <<<NBK, 1024, 0, stream>>>(bucketStart, bucketTotal, recs, dinv, nodeStart, nodePerm, N, E);
    prep_kernel   <<<ngrid, 256, 0, stream>>>(x, W1, dinv, g1h, N);
    agg1_kernel   <<<ngrid, 256, 0, stream>>>(nodeStart, recs, dinv, g1h, b1, W2, nodePerm, g2h, N);
    agg2_kernel   <<<ngrid, 256, 0, stream>>>(nodeStart, recs, dinv, g2h, b2, nodePerm, out, N);
}

// Round 8
// 590.779 us; speedup vs baseline: 1.0608x; 1.0608x over previous
//
#include <hip/hip_runtime.h>
#include <hip/hip_fp16.h>
#include <math.h>

#define NN 500000
#define BSZ 512                      // nodes per bucket
#define NBK ((NN + BSZ - 1) / BSZ)   // 977 buckets
#define SCH 8192                     // staging chunk (edges) = part granularity
#define KMAX 20                      // max recs/thread in sort (20*1024 >> max bucket ~16.9K)
#define SZMAX 17408                  // LDS sort buffer (max bucket ~16.2K edges + pad)

typedef __attribute__((ext_vector_type(4))) _Float16 half4;
typedef __attribute__((ext_vector_type(2))) _Float16 half2v;
typedef __attribute__((ext_vector_type(4))) int int4v;
typedef __attribute__((ext_vector_type(2))) float float2v;

// ---------- pass 1: per-chunk bucket histogram; NO global atomics ----------
__global__ void hist_kernel(const int* __restrict__ col, unsigned short* __restrict__ blkCnt,
                            int E, int nch) {
    __shared__ int cnt[4 * 1024];
    int t = threadIdx.x;
    for (int i = t; i < 4096; i += 256) cnt[i] = 0;
    __syncthreads();
    int base = blockIdx.x * (4 * SCH);
    int end = base + 4 * SCH; if (end > E) end = E;
    for (int j = base + t * 4; j < end; j += 1024) {
        int4v c = __builtin_nontemporal_load(reinterpret_cast<const int4v*>(col + j));
        int sub = (j - base) >> 13;                        // chunk within block (0..3)
        atomicAdd(&cnt[sub * 1024 + (c.x >> 9)], 1);
        atomicAdd(&cnt[sub * 1024 + (c.y >> 9)], 1);
        atomicAdd(&cnt[sub * 1024 + (c.z >> 9)], 1);
        atomicAdd(&cnt[sub * 1024 + (c.w >> 9)], 1);
    }
    __syncthreads();
    int chunk0 = blockIdx.x * 4;
#pragma unroll
    for (int s = 0; s < 4; ++s) {
        int c = chunk0 + s;
        if (c >= nch) break;
        for (int b = t; b < 1024; b += 256)
            blkCnt[(size_t)c * 1024 + b] = (unsigned short)cnt[s * 1024 + b];
    }
}

// ---------- pass 2: per-bucket SEQUENTIAL prefix across chunks, in place ---
__global__ void colscan_kernel(unsigned short* __restrict__ blkCnt,
                               int* __restrict__ bucketTotal, int nch) {
    __shared__ int ls[64][5];
    int t = threadIdx.x;
    int cl = t & 3;            // bucket lane (4 buckets/block)
    int bk = t >> 2;           // strip 0..63
    int b = blockIdx.x * 4 + cl;
    int cps = (nch + 63) >> 6; // chunks per strip (contiguous)
    int c0 = bk * cps;
    int c1 = c0 + cps; if (c1 > nch) c1 = nch;
    int run = 0;
    for (int c = c0; c < c1; ++c)
        run += blkCnt[(size_t)c * 1024 + b];
    ls[bk][cl] = run;
    __syncthreads();
    if (t < 4) {               // serial exclusive scan over the 64 strips
        int r = 0;
        for (int k = 0; k < 64; ++k) { int v = ls[k][t]; ls[k][t] = r; r += v; }
        bucketTotal[blockIdx.x * 4 + t] = r;
    }
    __syncthreads();
    int running = ls[bk][cl];
    for (int c = c0; c < c1; ++c) {
        size_t idx = (size_t)c * 1024 + b;
        int v = blkCnt[idx];
        blkCnt[idx] = (unsigned short)running;   // prefix <= bucket total ~17K < 65536
        running += v;
    }
}

// ---------- pass 3: exclusive scan of 1024 bucket totals (1 block) ---------
__global__ void scan_kernel(const int* __restrict__ bucketTotal, int* __restrict__ bucketStart) {
    __shared__ int ls[1024];
    int t = threadIdx.x;
    int v = bucketTotal[t];
    ls[t] = v;
    __syncthreads();
    for (int off = 1; off < 1024; off <<= 1) {
        int u = (t >= off) ? ls[t - off] : 0;
        __syncthreads();
        ls[t] += u;
        __syncthreads();
    }
    bucketStart[t] = ls[t] - v;  // exclusive
}

// ---------- pass 4: partition with LDS staging; NO global atomics ----------
__global__ __launch_bounds__(256) void part_kernel(const int* __restrict__ row,
                                                   const int* __restrict__ col,
                                                   const int* __restrict__ bucketStart,
                                                   const int* __restrict__ bucketTotal,
                                                   const unsigned short* __restrict__ blkPre,
                                                   int* __restrict__ recs, int E, int nch) {
    __shared__ int gbase[1024];
    __shared__ int lexcl[1024];
    __shared__ int cursor[1024];
    __shared__ int ts[256];
    __shared__ int srt[SCH];
    __shared__ unsigned short bkt[SCH];
    int t = threadIdx.x;
    int chunk = blockIdx.x;
    const unsigned short* pre = blkPre + (size_t)chunk * 1024;
    const unsigned short* nxt = blkPre + (size_t)(chunk + 1) * 1024;  // pad row exists
    bool last = (chunk == nch - 1);
    int myc[4];
#pragma unroll
    for (int k = 0; k < 4; ++k) {
        int b = t * 4 + k;
        int p = pre[b];
        int n = last ? bucketTotal[b] : (int)nxt[b];
        myc[k] = n - p;
        gbase[b] = bucketStart[b] + p;
    }
    int tsum = myc[0] + myc[1] + myc[2] + myc[3];
    ts[t] = tsum;
    __syncthreads();
    for (int off = 1; off < 256; off <<= 1) {
        int u = (t >= off) ? ts[t - off] : 0;
        __syncthreads();
        ts[t] += u;
        __syncthreads();
    }
    int r = ts[t] - tsum;      // exclusive over threads
#pragma unroll
    for (int k = 0; k < 4; ++k) {
        int b = t * 4 + k;
        lexcl[b] = r;
        cursor[b] = r;
        r += myc[k];
    }
    __syncthreads();
    // phase 1: rank + stage into LDS (bucket-sorted)
    int base = chunk * SCH;
    int end = base + SCH; if (end > E) end = E;
    for (int j = base + t * 4; j < end; j += 1024) {
        int4v rr = __builtin_nontemporal_load(reinterpret_cast<const int4v*>(row + j));
        int4v cc = __builtin_nontemporal_load(reinterpret_cast<const int4v*>(col + j));
        int b, rk;
        b = cc.x >> 9; rk = atomicAdd(&cursor[b], 1); srt[rk] = (rr.x << 9) | (cc.x & 511); bkt[rk] = (unsigned short)b;
        b = cc.y >> 9; rk = atomicAdd(&cursor[b], 1); srt[rk] = (rr.y << 9) | (cc.y & 511); bkt[rk] = (unsigned short)b;
        b = cc.z >> 9; rk = atomicAdd(&cursor[b], 1); srt[rk] = (rr.z << 9) | (cc.z & 511); bkt[rk] = (unsigned short)b;
        b = cc.w >> 9; rk = atomicAdd(&cursor[b], 1); srt[rk] = (rr.w << 9) | (cc.w & 511); bkt[rk] = (unsigned short)b;
    }
    __syncthreads();
    // phase 2: flush contiguous bucket runs
    int m = end - base;
    for (int p = t; p < m; p += 256) {
        int b = bkt[p];
        recs[gbase[b] + (p - lexcl[b])] = srt[p];
    }
}

// ---------- pass 5: per-bucket counting sort, LDS-staged output ------------
__global__ __launch_bounds__(1024) void sort_kernel(const int* __restrict__ bucketStart,
                                                    const int* __restrict__ bucketTotal,
                                                    int* __restrict__ recs,
                                                    float* __restrict__ dinv,
                                                    int* __restrict__ nodeStart, int N, int E) {
    __shared__ int cnt[BSZ];
    __shared__ int sc[BSZ];
    __shared__ int srtS[SZMAX];
    int t = threadIdx.x, b = blockIdx.x;
    int s = bucketStart[b], m = bucketTotal[b];
    int v[KMAX];
#pragma unroll
    for (int k = 0; k < KMAX; ++k) {
        int idx = t + k * 1024;
        v[k] = (idx < m) ? recs[s + idx] : -1;
    }
    if (t < BSZ) cnt[t] = 0;
    __syncthreads();
#pragma unroll
    for (int k = 0; k < KMAX; ++k)
        if (v[k] >= 0) atomicAdd(&cnt[v[k] & 511], 1);
    __syncthreads();
    if (t < BSZ) sc[t] = cnt[t];
    __syncthreads();
    for (int off = 1; off < BSZ; off <<= 1) {
        int u = 0;
        if (t < BSZ && t >= off) u = sc[t - off];
        __syncthreads();
        if (t < BSZ) sc[t] += u;
        __syncthreads();
    }
    if (t < BSZ) {
        int excl = sc[t] - cnt[t];
        int node = b * BSZ + t;
        if (node < N) {
            nodeStart[node] = s + excl;
            dinv[node] = rsqrtf((float)cnt[t] + 1.0f);
        }
        cnt[t] = excl;
    }
    if (b == NBK - 1 && t == 0) nodeStart[N] = E;
    __syncthreads();
#pragma unroll
    for (int k = 0; k < KMAX; ++k) {
        if (v[k] >= 0) {
            int rk = atomicAdd(&cnt[v[k] & 511], 1);
            srtS[rk] = v[k] >> 9;          // random LDS write: ~free
        }
    }
    __syncthreads();
    for (int p = t; p < m; p += 1024)      // coalesced global write
        recs[s + p] = srtS[p];
}

// ---------- prep: g1 = fp16( dinv * (x @ W1) ) -----------------------------
__global__ __launch_bounds__(256) void prep_kernel(const float* __restrict__ x,
                                                   const float* __restrict__ W1,
                                                   const float* __restrict__ dinv,
                                                   half4* __restrict__ g1h, int N) {
    __shared__ float xs[256 * 9];
    int t = threadIdx.x;
    int base = blockIdx.x * 256;
    int nval = (N - base < 256 ? N - base : 256) * 9;
    const float* xb = x + (size_t)base * 9;
    for (int k = t; k < nval; k += 256) xs[k] = xb[k];
    __syncthreads();
    int i = base + t;
    if (i >= N) return;
    float d = dinv[i];
    float acc0 = 0.f, acc1 = 0.f, acc2 = 0.f, acc3 = 0.f;
#pragma unroll
    for (int k = 0; k < 9; ++k) {
        float xv = xs[t * 9 + k];
        acc0 += xv * W1[k * 4 + 0];
        acc1 += xv * W1[k * 4 + 1];
        acc2 += xv * W1[k * 4 + 2];
        acc3 += xv * W1[k * 4 + 3];
    }
    half4 h;
    h.x = (_Float16)(d * acc0);
    h.y = (_Float16)(d * acc1);
    h.z = (_Float16)(d * acc2);
    h.w = (_Float16)(d * acc3);
    g1h[i] = h;
}

// ---------- L1-bypass gather loads (sc0 via agent-scope relaxed atomic) ----
// Theory: divergent gathers are L1-MSHR-throughput-limited (~32 fills / ~190
// cyc L2 latency = 5.9 cyc/line = the measured 5.6 cyc/gather). Agent-scope
// atomic loads bypass L1 allocation -> straight to L2's deeper queue.
__device__ __forceinline__ half4 ldg_l2(const half4* p) {
    unsigned long long v = __hip_atomic_load(reinterpret_cast<const unsigned long long*>(p),
                                             __ATOMIC_RELAXED, __HIP_MEMORY_SCOPE_AGENT);
    union { unsigned long long u; half4 h; } c; c.u = v; return c.h;
}
__device__ __forceinline__ half2v ldg_l2b(const half2v* p) {
    unsigned int v = __hip_atomic_load(reinterpret_cast<const unsigned int*>(p),
                                       __ATOMIC_RELAXED, __HIP_MEMORY_SCOPE_AGENT);
    union { unsigned int u; half2v h; } c; c.u = v; return c.h;
}

#define NTL(p) __builtin_nontemporal_load(p)

// ---------- agg layer 1: CSR gather, L1-bypass gathers ---------------------
__global__ __launch_bounds__(256) void agg1_kernel(const int* __restrict__ nodeStart,
                                                   const int* __restrict__ srows,
                                                   const float* __restrict__ dinv,
                                                   const half4* __restrict__ g1h,
                                                   const float* __restrict__ b1,
                                                   const float* __restrict__ W2,
                                                   half2v* __restrict__ g2h, int N) {
    int i = blockIdx.x * blockDim.x + threadIdx.x;
    if (i >= N) return;
    int s = nodeStart[i], e = nodeStart[i + 1];
    float a0 = 0.f, a1 = 0.f, a2 = 0.f, a3 = 0.f;
    int j = s;
    // scalar prologue up to 16B alignment
    for (; j < e && (j & 3); ++j) {
        half4 g = ldg_l2(g1h + NTL(srows + j));
        a0 += (float)g.x; a1 += (float)g.y; a2 += (float)g.z; a3 += (float)g.w;
    }
    // 16-edge chunks: 16 independent gathers per batch
    for (; j + 15 < e; j += 16) {
        int4v q0 = NTL(reinterpret_cast<const int4v*>(srows + j));
        int4v q1 = NTL(reinterpret_cast<const int4v*>(srows + j + 4));
        int4v q2 = NTL(reinterpret_cast<const int4v*>(srows + j + 8));
        int4v q3 = NTL(reinterpret_cast<const int4v*>(srows + j + 12));
        half4 g0 = ldg_l2(g1h + q0.x), g1 = ldg_l2(g1h + q0.y), g2 = ldg_l2(g1h + q0.z), g3 = ldg_l2(g1h + q0.w);
        half4 g4 = ldg_l2(g1h + q1.x), g5 = ldg_l2(g1h + q1.y), g6 = ldg_l2(g1h + q1.z), g7 = ldg_l2(g1h + q1.w);
        half4 g8 = ldg_l2(g1h + q2.x), g9 = ldg_l2(g1h + q2.y), gA = ldg_l2(g1h + q2.z), gB = ldg_l2(g1h + q2.w);
        half4 gC = ldg_l2(g1h + q3.x), gD = ldg_l2(g1h + q3.y), gE = ldg_l2(g1h + q3.z), gF = ldg_l2(g1h + q3.w);
        a0 += (((float)g0.x + (float)g1.x) + ((float)g2.x + (float)g3.x)) +
              (((float)g4.x + (float)g5.x) + ((float)g6.x + (float)g7.x)) +
              (((float)g8.x + (float)g9.x) + ((float)gA.x + (float)gB.x)) +
              (((float)gC.x + (float)gD.x) + ((float)gE.x + (float)gF.x));
        a1 += (((float)g0.y + (float)g1.y) + ((float)g2.y + (float)g3.y)) +
              (((float)g4.y + (float)g5.y) + ((float)g6.y + (float)g7.y)) +
              (((float)g8.y + (float)g9.y) + ((float)gA.y + (float)gB.y)) +
              (((float)gC.y + (float)gD.y) + ((float)gE.y + (float)gF.y));
        a2 += (((float)g0.z + (float)g1.z) + ((float)g2.z + (float)g3.z)) +
              (((float)g4.z + (float)g5.z) + ((float)g6.z + (float)g7.z)) +
              (((float)g8.z + (float)g9.z) + ((float)gA.z + (float)gB.z)) +
              (((float)gC.z + (float)gD.z) + ((float)gE.z + (float)gF.z));
        a3 += (((float)g0.w + (float)g1.w) + ((float)g2.w + (float)g3.w)) +
              (((float)g4.w + (float)g5.w) + ((float)g6.w + (float)g7.w)) +
              (((float)g8.w + (float)g9.w) + ((float)gA.w + (float)gB.w)) +
              (((float)gC.w + (float)gD.w) + ((float)gE.w + (float)gF.w));
    }
    for (; j + 3 < e; j += 4) {
        int4v r4 = NTL(reinterpret_cast<const int4v*>(srows + j));
        half4 g0 = ldg_l2(g1h + r4.x);
        half4 g1 = ldg_l2(g1h + r4.y);
        half4 g2 = ldg_l2(g1h + r4.z);
        half4 g3 = ldg_l2(g1h + r4.w);
        a0 += ((float)g0.x + (float)g1.x) + ((float)g2.x + (float)g3.x);
        a1 += ((float)g0.y + (float)g1.y) + ((float)g2.y + (float)g3.y);
        a2 += ((float)g0.z + (float)g1.z) + ((float)g2.z + (float)g3.z);
        a3 += ((float)g0.w + (float)g1.w) + ((float)g2.w + (float)g3.w);
    }
    for (; j < e; ++j) {
        half4 g = ldg_l2(g1h + NTL(srows + j));
        a0 += (float)g.x; a1 += (float)g.y; a2 += (float)g.z; a3 += (float)g.w;
    }
    half4 self = g1h[i];
    float di = dinv[i];
    float t0 = tanhf(di * (a0 + (float)self.x) + b1[0]);
    float t1 = tanhf(di * (a1 + (float)self.y) + b1[1]);
    float t2 = tanhf(di * (a2 + (float)self.z) + b1[2]);
    float t3 = tanhf(di * (a3 + (float)self.w) + b1[3]);
    float o0 = t0 * W2[0] + t1 * W2[2] + t2 * W2[4] + t3 * W2[6];
    float o1 = t0 * W2[1] + t1 * W2[3] + t2 * W2[5] + t3 * W2[7];
    half2v g2o;
    g2o.x = (_Float16)(di * o0);
    g2o.y = (_Float16)(di * o1);
    g2h[i] = g2o;
}

// ---------- agg layer 2: CSR gather, L1-bypass gathers ---------------------
__global__ __launch_bounds__(256) void agg2_kernel(const int* __restrict__ nodeStart,
                                                   const int* __restrict__ srows,
                                                   const float* __restrict__ dinv,
                                                   const half2v* __restrict__ g2h,
                                                   const float* __restrict__ b2,
                                                   float* __restrict__ out, int N) {
    int i = blockIdx.x * blockDim.x + threadIdx.x;
    if (i >= N) return;
    int s = nodeStart[i], e = nodeStart[i + 1];
    float a0 = 0.f, a1 = 0.f;
    int j = s;
    for (; j < e && (j & 3); ++j) {
        half2v g = ldg_l2b(g2h + NTL(srows + j));
        a0 += (float)g.x; a1 += (float)g.y;
    }
    for (; j + 15 < e; j += 16) {
        int4v q0 = NTL(reinterpret_cast<const int4v*>(srows + j));
        int4v q1 = NTL(reinterpret_cast<const int4v*>(srows + j + 4));
        int4v q2 = NTL(reinterpret_cast<const int4v*>(srows + j + 8));
        int4v q3 = NTL(reinterpret_cast<const int4v*>(srows + j + 12));
        half2v g0 = ldg_l2b(g2h + q0.x), g1 = ldg_l2b(g2h + q0.y), g2 = ldg_l2b(g2h + q0.z), g3 = ldg_l2b(g2h + q0.w);
        half2v g4 = ldg_l2b(g2h + q1.x), g5 = ldg_l2b(g2h + q1.y), g6 = ldg_l2b(g2h + q1.z), g7 = ldg_l2b(g2h + q1.w);
        half2v g8 = ldg_l2b(g2h + q2.x), g9 = ldg_l2b(g2h + q2.y), gA = ldg_l2b(g2h + q2.z), gB = ldg_l2b(g2h + q2.w);
        half2v gC = ldg_l2b(g2h + q3.x), gD = ldg_l2b(g2h + q3.y), gE = ldg_l2b(g2h + q3.z), gF = ldg_l2b(g2h + q3.w);
        a0 += (((float)g0.x + (float)g1.x) + ((float)g2.x + (float)g3.x)) +
              (((float)g4.x + (float)g5.x) + ((float)g6.x + (float)g7.x)) +
              (((float)g8.x + (float)g9.x) + ((float)gA.x + (float)gB.x)) +
              (((float)gC.x + (float)gD.x) + ((float)gE.x + (float)gF.x));
        a1 += (((float)g0.y + (float)g1.y) + ((float)g2.y + (float)g3.y)) +
              (((float)g4.y + (float)g5.y) + ((float)g6.y + (float)g7.y)) +
              (((float)g8.y + (float)g9.y) + ((float)gA.y + (float)gB.y)) +
              (((float)gC.y + (float)gD.y) + ((float)gE.y + (float)gF.y));
    }
    for (; j + 3 < e; j += 4) {
        int4v r4 = NTL(reinterpret_cast<const int4v*>(srows + j));
        half2v g0 = ldg_l2b(g2h + r4.x);
        half2v g1 = ldg_l2b(g2h + r4.y);
        half2v g2 = ldg_l2b(g2h + r4.z);
        half2v g3 = ldg_l2b(g2h + r4.w);
        a0 += ((float)g0.x + (float)g1.x) + ((float)g2.x + (float)g3.x);
        a1 += ((float)g0.y + (float)g1.y) + ((float)g2.y + (float)g3.y);
    }
    for (; j < e; ++j) {
        half2v g = ldg_l2b(g2h + NTL(srows + j));
        a0 += (float)g.x; a1 += (float)g.y;
    }
    half2v self = g2h[i];
    float di = dinv[i];
    float2v o;
    o.x = di * (a0 + (float)self.x) + b2[0];
    o.y = di * (a1 + (float)self.y) + b2[1];
    __builtin_nontemporal_store(o, reinterpret_cast<float2v*>(out) + i);
}

extern "C" void kernel_launch(void* const* d_in, const int* in_sizes, int n_in,
                              void* d_out, int out_size, void* d_ws, size_t ws_size,
                              hipStream_t stream) {
    const float* x  = (const float*)d_in[0];
    const int*   ei = (const int*)d_in[1];   // [2, E] int32
    const float* W1 = (const float*)d_in[2];
    const float* b1 = (const float*)d_in[3];
    const float* W2 = (const float*)d_in[4];
    const float* b2 = (const float*)d_in[5];
    float* out = (float*)d_out;

    const int N = NN;
    const int E = in_sizes[1] / 2;           // 16,000,000
    const int* row = ei;
    const int* col = ei + E;

    const int nch = (E + SCH - 1) / SCH;     // 1954 staging chunks

    char* ws = (char*)d_ws;
    size_t off = 0;
    int* bucketTotal = (int*)(ws + off);            off += 4096;
    int* bucketStart = (int*)(ws + off);            off += 4096;
    off = 16384;
    unsigned short* blkCnt = (unsigned short*)(ws + off);
    off += (size_t)(nch + 1) * 1024 * 2;            // ~4.0 MB (pad row for part's nxt)
    off = (off + 15) & ~(size_t)15;
    float*  dinv      = (float*)(ws + off);         off += (size_t)NN * 4;
    off = (off + 15) & ~(size_t)15;
    half4*  g1h       = (half4*)(ws + off);         off += (size_t)NN * 8;
    off = (off + 15) & ~(size_t)15;
    half2v* g2h       = (half2v*)(ws + off);        off += (size_t)NN * 4;
    off = (off + 15) & ~(size_t)15;
    int*    nodeStart = (int*)(ws + off);           off += (size_t)(NN + 1) * 4;
    off = (off + 15) & ~(size_t)15;
    int*    recs      = (int*)(ws + off);

    // zero the blkCnt pad row (speculatively read by part's nxt on the last chunk)
    (void)hipMemsetAsync(blkCnt + (size_t)nch * 1024, 0, 2048, stream);

    const int ngrid = (N + 255) / 256;
    const int hgrid = (nch + 3) / 4;

    hist_kernel   <<<hgrid, 256, 0, stream>>>(col, blkCnt, E, nch);
    colscan_kernel<<<256, 256, 0, stream>>>(blkCnt, bucketTotal, nch);
    scan_kernel   <<<1, 1024, 0, stream>>>(bucketTotal, bucketStart);
    part_kernel   <<<nch, 256, 0, stream>>>(row, col, bucketStart, bucketTotal, blkCnt, recs, E, nch);
    sort_kernel   <<<NBK, 1024, 0, stream>>>(bucketStart, bucketTotal, recs, dinv, nodeStart, N, E);
    prep_kernel   <<<ngrid, 256, 0, stream>>>(x, W1, dinv, g1h, N);
    agg1_kernel   <<<ngrid, 256, 0, stream>>>(nodeStart, recs, dinv, g1h, b1, W2, g2h, N);
    agg2_kernel   <<<ngrid, 256, 0, stream>>>(nodeStart, recs, dinv, g2h, b2, out, N);
}